// Round 10
// baseline (1553.206 us; speedup 1.0000x reference)
//
#include <hip/hip_runtime.h>

// VGAE: 8 GCN layers, N=100000, E=1.6M, dims 64/128 — bf16 + MFMA.
// GCN(x,W,b) = P(x)@W + b, P linear. Props are XCD-SLICED: blockIdx&7 = feature
// slice -> lands on one XCD (round-robin dispatch), slice working set (1.6-3.2MB)
// fits that XCD's 4MB L2 -> gathers become L2-hits instead of 1.9TB/s random L3.
// CSR packed to 4B/edge ((src<<15)|bf16w&0x7FFF) since each prop re-walks it 8x.
// T uses interleaved [tmu-oct|tsi-oct] per 16 cols so mu/si/z epilogue is slice-local.

typedef short bf16x8 __attribute__((ext_vector_type(8)));
typedef float f32x4 __attribute__((ext_vector_type(4)));

__device__ __forceinline__ ushort f2bf(float f) {           // RNE
    uint x = __float_as_uint(f);
    uint r = x + 0x7FFFu + ((x >> 16) & 1u);
    return (ushort)(r >> 16);
}
__device__ __forceinline__ float bf2f(ushort h) {
    return __uint_as_float(((uint)h) << 16);
}
// acc[0..7] += w * bf16x8-in-uint4
__device__ __forceinline__ void fma8(float* acc, uint4 v, float w) {
    acc[0] = fmaf(w, __uint_as_float(v.x << 16), acc[0]);
    acc[1] = fmaf(w, __uint_as_float(v.x & 0xFFFF0000u), acc[1]);
    acc[2] = fmaf(w, __uint_as_float(v.y << 16), acc[2]);
    acc[3] = fmaf(w, __uint_as_float(v.y & 0xFFFF0000u), acc[3]);
    acc[4] = fmaf(w, __uint_as_float(v.z << 16), acc[4]);
    acc[5] = fmaf(w, __uint_as_float(v.z & 0xFFFF0000u), acc[5]);
    acc[6] = fmaf(w, __uint_as_float(v.w << 16), acc[6]);
    acc[7] = fmaf(w, __uint_as_float(v.w & 0xFFFF0000u), acc[7]);
}

// ------------------------------------------------------------------ counts: deg + binned histogram
__global__ __launch_bounds__(1024) void counts_kernel(const int* __restrict__ dst,
        int* __restrict__ deg, int* __restrict__ bc0, int E, int NB, int shift) {
    __shared__ int h[8192];
    for (int j = threadIdx.x; j < NB; j += 1024) h[j] = 0;
    __syncthreads();
    int stride = gridDim.x * 1024;
    for (int i = blockIdx.x * 1024 + threadIdx.x; i < E; i += stride) {
        int d = dst[i];
        atomicAdd(&deg[d], 1);
        atomicAdd(&h[d >> shift], 1);
    }
    __syncthreads();
    for (int j = threadIdx.x; j < NB; j += 1024) {
        int v = h[j];
        if (v) atomicAdd(&bc0[j], v);
    }
}

__global__ void dinv_kernel(const int* __restrict__ deg, float* __restrict__ dinv, int N) {
    int i = blockIdx.x * blockDim.x + threadIdx.x;
    if (i < N) dinv[i] = rsqrtf((float)(deg[i] + 1));
}

// ------------------------------------------------------------------ scan
__global__ __launch_bounds__(1024) void scan_block_kernel(const int* __restrict__ in,
                                                          int* __restrict__ out,
                                                          int* __restrict__ bsum, int n) {
    __shared__ int s[1024];
    int i = blockIdx.x * 1024 + threadIdx.x;
    int v = (i < n) ? in[i] : 0;
    s[threadIdx.x] = v;
    __syncthreads();
    for (int off = 1; off < 1024; off <<= 1) {
        int t = (threadIdx.x >= off) ? s[threadIdx.x - off] : 0;
        __syncthreads();
        s[threadIdx.x] += t;
        __syncthreads();
    }
    if (i < n) out[i] = s[threadIdx.x] - v;
    if (threadIdx.x == 1023) bsum[blockIdx.x] = s[1023];
}

__global__ __launch_bounds__(1024) void scan_partials_kernel(int* __restrict__ bsum, int nb) {
    __shared__ int s[1024];
    int v = (threadIdx.x < nb) ? bsum[threadIdx.x] : 0;
    s[threadIdx.x] = v;
    __syncthreads();
    for (int off = 1; off < 1024; off <<= 1) {
        int t = (threadIdx.x >= off) ? s[threadIdx.x - off] : 0;
        __syncthreads();
        s[threadIdx.x] += t;
        __syncthreads();
    }
    if (threadIdx.x < nb) bsum[threadIdx.x] = s[threadIdx.x] - v;
}

__global__ __launch_bounds__(1024) void scan_add_kernel(int* __restrict__ arr,
                                                        const int* __restrict__ bsum, int n, int total) {
    int i = blockIdx.x * 1024 + threadIdx.x;
    if (i < n) arr[i] += bsum[blockIdx.x];
    if (i == 0) arr[n] = total;
}

// ------------------------------------------------------------------ bin scatter + place (packed 4B csr)
__global__ void scatter_kernel(const int* __restrict__ src, const int* __restrict__ dst,
                               const int* __restrict__ bin_start, int* __restrict__ bc1,
                               int2* __restrict__ ebuf, int E, int shift) {
    int i = blockIdx.x * blockDim.x + threadIdx.x;
    if (i < E) {
        int d = dst[i];
        int b = d >> shift;
        int pos = bin_start[b] + atomicAdd(&bc1[b], 1);
        ebuf[pos] = make_int2(src[i], d);
    }
}

__global__ void place2_kernel(const int2* __restrict__ ebuf, const int* __restrict__ row_start,
                              int* __restrict__ cnt, uint* __restrict__ csrp,
                              const float* __restrict__ dinv, int E) {
    int i = blockIdx.x * blockDim.x + threadIdx.x;
    if (i < E) {
        int2 e = ebuf[i];
        int pos = row_start[e.y] + atomicAdd(&cnt[e.y], 1);
        uint wb = (uint)f2bf(dinv[e.x] * dinv[e.y]) & 0x7FFFu;   // weight > 0: sign bit 0
        csrp[pos] = ((uint)e.x << 15) | wb;
    }
}

// ------------------------------------------------------------------ cvec[j] = dinv_j^2 + sum_w
__global__ void rowsum_kernel(const uint* __restrict__ csrp, const int* __restrict__ row_start,
                              const float* __restrict__ dinv, float* __restrict__ cvec, int N) {
    int j = blockIdx.x * blockDim.x + threadIdx.x;
    if (j >= N) return;
    float s = dinv[j] * dinv[j];
    int b = row_start[j], e = row_start[j + 1];
    for (int k = b; k < e; ++k) s += __uint_as_float((csrp[k] & 0x7FFFu) << 16);
    cvec[j] = s;
}

// ------------------------------------------------------------------ Wc = w_z@w_d0 packed bf16, bzw = b_z@w_d0
__global__ void wcpack_kernel(const float* __restrict__ w_z, const float* __restrict__ b_z,
                              const float* __restrict__ w_d0,
                              ushort* __restrict__ P_wc, float* __restrict__ bzw) {
    int o = blockIdx.x * 256 + threadIdx.x;
    if (o >= 65 * 128) return;
    int i = o >> 7, j = o & 127;
    float s = 0.f;
    for (int k = 0; k < 128; ++k) {
        float a = (i < 64) ? w_z[i * 128 + k] : b_z[k];
        s = fmaf(a, w_d0[k * 128 + j], s);
    }
    if (i < 64) {
        int c = j >> 4, kb = i >> 5, l = ((i >> 3) & 3) * 16 + (j & 15), e = i & 7;
        P_wc[(size_t)((c * 2 + kb) * 64 + l) * 8 + e] = f2bf(s);
    } else bzw[j] = s;
}

// ------------------------------------------------------------------ weight packs (6 weights, 1 launch)
__device__ __forceinline__ void pack_one(const float* __restrict__ W, ushort* __restrict__ P,
                                         int KI, int KO, int idx) {
    if (idx >= KI * KO) return;
    int e = idx & 7, l = (idx >> 3) & 63, t = idx >> 9;
    int KB = KI / 32;
    int c = t / KB, kb = t % KB;
    int k = kb * 32 + ((l >> 4) << 3) + e, col = c * 16 + (l & 15);
    P[idx] = f2bf(W[(size_t)k * KO + col]);
}

__global__ void megapack_kernel(const float* w_in, const float* w_mu0, const float* w_si0,
                                const float* w_mu, const float* w_si, const float* w_out,
                                ushort* P_in, ushort* P_mu0, ushort* P_si0,
                                ushort* P_mu, ushort* P_si, ushort* P_out) {
    int b = blockIdx.x, tid = threadIdx.x;
    if (b < 32)       pack_one(w_in,  P_in,  64, 128,  (b - 0)   * 256 + tid);
    else if (b < 96)  pack_one(w_mu0, P_mu0, 128, 128, (b - 32)  * 256 + tid);
    else if (b < 160) pack_one(w_si0, P_si0, 128, 128, (b - 96)  * 256 + tid);
    else if (b < 192) pack_one(w_mu,  P_mu,  128, 64,  (b - 160) * 256 + tid);
    else if (b < 224) pack_one(w_si,  P_si,  128, 64,  (b - 192) * 256 + tid);
    else              pack_one(w_out, P_out, 128, 128, (b - 224) * 256 + tid);
}

// ------------------------------------------------------------------ f32 -> bf16
__global__ void cvt8_kernel(const float* __restrict__ in, ushort* __restrict__ out, int n8) {
    int i = blockIdx.x * 256 + threadIdx.x;
    if (i >= n8) return;
    float4 a = ((const float4*)in)[i * 2];
    float4 b = ((const float4*)in)[i * 2 + 1];
    bf16x8 o;
    o[0] = (short)f2bf(a.x); o[1] = (short)f2bf(a.y);
    o[2] = (short)f2bf(a.z); o[3] = (short)f2bf(a.w);
    o[4] = (short)f2bf(b.x); o[5] = (short)f2bf(b.y);
    o[6] = (short)f2bf(b.z); o[7] = (short)f2bf(b.w);
    ((bf16x8*)out)[i] = o;
}

// ================================================================== XCD-sliced props
// blockIdx&7 = feature slice fs (lands on XCD fs via round-robin dispatch).

// ---- W=64: slice = 8 features (16B), 1 lane/edge, 4 node-groups of 16 lanes/wave.
__global__ __launch_bounds__(256) void sprop64_kernel(const ushort* __restrict__ xb,
        ushort* __restrict__ out, const int* __restrict__ row_start,
        const uint* __restrict__ csrp, const float* __restrict__ dinv, int N) {
    int b = blockIdx.x;
    int fs = b & 7, chunk = b >> 3;
    int wave = threadIdx.x >> 6, lane = threadIdx.x & 63;
    int grp = lane >> 4, slot = lane & 15;
    int node = chunk * 16 + wave * 4 + grp;
    if (node >= N) return;
    int beg = row_start[node], end = row_start[node + 1];
    const ushort* base_x = xb + (size_t)fs * 8;

    float acc[8] = {};
    for (int base = beg; base < end; base += 16) {
        int e = base + slot;
        bool v = e < end;
        uint ent = csrp[v ? e : 0];
        float w = v ? __uint_as_float((ent & 0x7FFFu) << 16) : 0.f;
        uint4 r = *(const uint4*)(base_x + (size_t)(ent >> 15) * 64);
        fma8(acc, r, w);
    }
    #pragma unroll
    for (int m = 1; m < 16; m <<= 1) {
        #pragma unroll
        for (int q = 0; q < 8; ++q) acc[q] += __shfl_xor(acc[q], m);
    }
    if (slot != 0) return;
    float d2 = dinv[node]; d2 *= d2;
    uint4 sv = *(const uint4*)(base_x + (size_t)node * 64);
    fma8(acc, sv, d2);
    bf16x8 o;
    #pragma unroll
    for (int q = 0; q < 8; ++q) o[q] = (short)f2bf(acc[q]);
    *(bf16x8*)(out + (size_t)node * 64 + fs * 8) = o;
}

// ---- W=128: slice = 16 features (32B), 2 lanes/edge (p=lane&1), 2 node-groups of 32 lanes.
__global__ __launch_bounds__(256) void sprop128_kernel(const ushort* __restrict__ xb,
        ushort* __restrict__ out, const int* __restrict__ row_start,
        const uint* __restrict__ csrp, const float* __restrict__ dinv, int N) {
    int b = blockIdx.x;
    int fs = b & 7, chunk = b >> 3;
    int wave = threadIdx.x >> 6, lane = threadIdx.x & 63;
    int grp = lane >> 5, slot = (lane >> 1) & 15, p = lane & 1;
    int node = chunk * 8 + wave * 2 + grp;
    if (node >= N) return;
    int beg = row_start[node], end = row_start[node + 1];
    const ushort* base_x = xb + (size_t)fs * 16 + p * 8;

    float acc[8] = {};
    for (int base = beg; base < end; base += 16) {
        int e = base + slot;
        bool v = e < end;
        uint ent = csrp[v ? e : 0];
        float w = v ? __uint_as_float((ent & 0x7FFFu) << 16) : 0.f;
        uint4 r = *(const uint4*)(base_x + (size_t)(ent >> 15) * 128);
        fma8(acc, r, w);
    }
    #pragma unroll
    for (int m = 2; m < 32; m <<= 1) {
        #pragma unroll
        for (int q = 0; q < 8; ++q) acc[q] += __shfl_xor(acc[q], m);
    }
    if (slot != 0) return;
    float d2 = dinv[node]; d2 *= d2;
    uint4 sv = *(const uint4*)(base_x + (size_t)node * 128);
    fma8(acc, sv, d2);
    bf16x8 o;
    #pragma unroll
    for (int q = 0; q < 8; ++q) o[q] = (short)f2bf(acc[q]);
    *(bf16x8*)(out + (size_t)node * 128 + fs * 16 + p * 8) = o;
}

// ---- smssz: sliced 128-prop of interleaved T -> mu (p=0), si (p=1), z.
__global__ __launch_bounds__(256) void smssz_kernel(const ushort* __restrict__ T,
        const int* __restrict__ row_start, const uint* __restrict__ csrp,
        const float* __restrict__ dinv, const float* __restrict__ b_mu,
        const float* __restrict__ b_si, const float* __restrict__ eps,
        float* __restrict__ M, float* __restrict__ S, ushort* __restrict__ zb, int N) {
    int b = blockIdx.x;
    int fs = b & 7, chunk = b >> 3;
    int wave = threadIdx.x >> 6, lane = threadIdx.x & 63;
    int grp = lane >> 5, slot = (lane >> 1) & 15, p = lane & 1;
    int node = chunk * 8 + wave * 2 + grp;
    if (node >= N) return;
    int beg = row_start[node], end = row_start[node + 1];
    const ushort* base_x = T + (size_t)fs * 16 + p * 8;

    float acc[8] = {};
    for (int base = beg; base < end; base += 16) {
        int e = base + slot;
        bool v = e < end;
        uint ent = csrp[v ? e : 0];
        float w = v ? __uint_as_float((ent & 0x7FFFu) << 16) : 0.f;
        uint4 r = *(const uint4*)(base_x + (size_t)(ent >> 15) * 128);
        fma8(acc, r, w);
    }
    #pragma unroll
    for (int m = 2; m < 32; m <<= 1) {
        #pragma unroll
        for (int q = 0; q < 8; ++q) acc[q] += __shfl_xor(acc[q], m);
    }
    // keep all lanes past here for the pair shfl; only slot==0 computes/stores
    float d2 = dinv[node]; d2 *= d2;
    uint4 sv = *(const uint4*)(base_x + (size_t)node * 128);
    fma8(acc, sv, d2);

    const float* bp = (p == 0) ? b_mu : b_si;
    int o = fs * 8;
    float val[8];
    #pragma unroll
    for (int q = 0; q < 8; ++q) {
        float t = acc[q] + bp[o + q];
        val[q] = (p == 0) ? fmaxf(t, 0.f) : 1.f / (1.f + __expf(-t));
    }
    float oth[8];
    #pragma unroll
    for (int q = 0; q < 8; ++q) oth[q] = __shfl_xor(val[q], 1);
    if (slot != 0) return;
    if (p == 0) {
        *(float4*)&M[(size_t)node * 64 + o]     = make_float4(val[0], val[1], val[2], val[3]);
        *(float4*)&M[(size_t)node * 64 + o + 4] = make_float4(val[4], val[5], val[6], val[7]);
        float4 e0v = *(const float4*)&eps[(size_t)node * 64 + o];
        float4 e1v = *(const float4*)&eps[(size_t)node * 64 + o + 4];
        float ev[8] = {e0v.x, e0v.y, e0v.z, e0v.w, e1v.x, e1v.y, e1v.z, e1v.w};
        bf16x8 z;
        #pragma unroll
        for (int q = 0; q < 8; ++q) z[q] = (short)f2bf(fmaf(oth[q], ev[q], val[q]));
        *(bf16x8*)(zb + (size_t)node * 64 + o) = z;
    } else {
        *(float4*)&S[(size_t)node * 64 + o]     = make_float4(val[0], val[1], val[2], val[3]);
        *(float4*)&S[(size_t)node * 64 + o + 4] = make_float4(val[4], val[5], val[6], val[7]);
    }
}

// ------------------------------------------------------------------ fused encoder GEMM chain (emits interleaved T)
__global__ __launch_bounds__(256) void encgemm_kernel(const ushort* __restrict__ PH,
        const bf16x8* __restrict__ Pmu0, const float* __restrict__ b_mu0,
        const bf16x8* __restrict__ Pmu,
        const bf16x8* __restrict__ Psi0, const float* __restrict__ b_si0,
        const bf16x8* __restrict__ Psi,
        ushort* __restrict__ T, int N) {
    constexpr int STR = 136;
    __shared__ __align__(16) ushort Ls[64 * STR];
    int w = threadIdx.x >> 6, l = threadIdx.x & 63;
    int lr = l & 15, lk = l >> 4;
    int rowbase = blockIdx.x * 64;
    int arow = rowbase + w * 16 + lr; if (arow > N - 1) arow = N - 1;

    bf16x8 aph[4];
    const ushort* pp = PH + (size_t)arow * 128 + lk * 8;
    #pragma unroll
    for (int kb = 0; kb < 4; ++kb) aph[kb] = *(const bf16x8*)(pp + kb * 32);

    int crow0 = w * 16 + lk * 4;
    int afrow = w * 16 + lr;

    #pragma unroll
    for (int c = 0; c < 8; ++c) {
        f32x4 acc = {0.f, 0.f, 0.f, 0.f};
        #pragma unroll
        for (int kb = 0; kb < 4; ++kb)
            acc = __builtin_amdgcn_mfma_f32_16x16x32_bf16(aph[kb], Pmu0[((size_t)c * 4 + kb) * 64 + l], acc, 0, 0, 0);
        float bv = b_mu0[c * 16 + lr];
        #pragma unroll
        for (int r = 0; r < 4; ++r)
            Ls[(crow0 + r) * STR + c * 16 + lr] = f2bf(fmaxf(acc[r] + bv, 0.f));
    }
    __syncthreads();
    bf16x8 am[4];
    #pragma unroll
    for (int kb = 0; kb < 4; ++kb) am[kb] = *(const bf16x8*)&Ls[afrow * STR + kb * 32 + lk * 8];
    f32x4 tmu[4];
    #pragma unroll
    for (int c = 0; c < 4; ++c) {
        f32x4 acc = {0.f, 0.f, 0.f, 0.f};
        #pragma unroll
        for (int kb = 0; kb < 4; ++kb)
            acc = __builtin_amdgcn_mfma_f32_16x16x32_bf16(am[kb], Pmu[((size_t)c * 4 + kb) * 64 + l], acc, 0, 0, 0);
        tmu[c] = acc;
    }
    __syncthreads();
    #pragma unroll
    for (int c = 0; c < 8; ++c) {
        f32x4 acc = {0.f, 0.f, 0.f, 0.f};
        #pragma unroll
        for (int kb = 0; kb < 4; ++kb)
            acc = __builtin_amdgcn_mfma_f32_16x16x32_bf16(aph[kb], Psi0[((size_t)c * 4 + kb) * 64 + l], acc, 0, 0, 0);
        float bv = b_si0[c * 16 + lr];
        #pragma unroll
        for (int r = 0; r < 4; ++r)
            Ls[(crow0 + r) * STR + c * 16 + lr] = f2bf(fmaxf(acc[r] + bv, 0.f));
    }
    __syncthreads();
    #pragma unroll
    for (int kb = 0; kb < 4; ++kb) am[kb] = *(const bf16x8*)&Ls[afrow * STR + kb * 32 + lk * 8];
    f32x4 tsi[4];
    #pragma unroll
    for (int c = 0; c < 4; ++c) {
        f32x4 acc = {0.f, 0.f, 0.f, 0.f};
        #pragma unroll
        for (int kb = 0; kb < 4; ++kb)
            acc = __builtin_amdgcn_mfma_f32_16x16x32_bf16(am[kb], Psi[((size_t)c * 4 + kb) * 64 + l], acc, 0, 0, 0);
        tsi[c] = acc;
    }
    __syncthreads();
    // interleaved T: feature j -> tmu col (j>>3)*16+(j&7), tsi col +8. j = c*16+lr.
    {
        int colm = ((lr >> 3) + 2 * 0) * 16;   // computed per c below
        (void)colm;
    }
    #pragma unroll
    for (int c = 0; c < 4; ++c) {
        int colm = c * 32 + (lr >> 3) * 16 + (lr & 7);
        #pragma unroll
        for (int r = 0; r < 4; ++r) {
            Ls[(crow0 + r) * STR + colm]     = f2bf(tmu[c][r]);
            Ls[(crow0 + r) * STR + colm + 8] = f2bf(tsi[c][r]);
        }
    }
    __syncthreads();
    for (int idx = threadIdx.x; idx < 64 * 16; idx += 256) {
        int row = idx >> 4, c8 = idx & 15;
        if (rowbase + row < N) {
            bf16x8 vv = *(const bf16x8*)&Ls[row * STR + c8 * 8];
            *(bf16x8*)(T + (size_t)(rowbase + row) * 128 + c8 * 8) = vv;
        }
    }
}

// ------------------------------------------------------------------ MFMA GEMM
template <int KI, int KO, int EPI, int OUT>
__global__ __launch_bounds__(256) void mgemm_kernel(const ushort* __restrict__ Xb,
                                                    const bf16x8* __restrict__ Wp,
                                                    const float* __restrict__ bias,
                                                    const float* __restrict__ bias2,
                                                    const float* __restrict__ cvec,
                                                    void* __restrict__ outp, int ostride, int N) {
    constexpr int KB = KI / 32;
    constexpr int CT = KO / 16;
    constexpr size_t LSB = (OUT == 1) ? (size_t)64 * KO * 4 : (size_t)64 * KO * 2;
    __shared__ __align__(16) char LsRaw[LSB];

    int w = threadIdx.x >> 6, l = threadIdx.x & 63;
    int lr = l & 15, lk = l >> 4;
    int rowbase = blockIdx.x * 64;
    int r0 = rowbase + w * 16;

    int arow = r0 + lr; if (arow > N - 1) arow = N - 1;
    bf16x8 a[KB];
    const ushort* xp = Xb + (size_t)arow * KI + lk * 8;
    #pragma unroll
    for (int kb = 0; kb < KB; ++kb) a[kb] = *(const bf16x8*)(xp + kb * 32);

    float cv[4];
    if constexpr (EPI == 3) {
        #pragma unroll
        for (int r = 0; r < 4; ++r) {
            int rr = r0 + lk * 4 + r;
            cv[r] = cvec[rr < N ? rr : 0];
        }
    }

    #pragma unroll
    for (int c = 0; c < CT; ++c) {
        f32x4 acc = {0.f, 0.f, 0.f, 0.f};
        #pragma unroll
        for (int kb = 0; kb < KB; ++kb)
            acc = __builtin_amdgcn_mfma_f32_16x16x32_bf16(a[kb], Wp[((size_t)c * KB + kb) * 64 + l], acc, 0, 0, 0);
        int col = c * 16 + lr;
        float bv = 0.f, b2v = 0.f;
        if constexpr (EPI >= 1) bv = bias[col];
        if constexpr (EPI == 3) b2v = bias2[col];
        #pragma unroll
        for (int r = 0; r < 4; ++r) {
            float v = acc[r];
            if constexpr (EPI == 1) v += bv;
            if constexpr (EPI == 2) v = fmaxf(v + bv, 0.f);
            if constexpr (EPI == 3) v = fmaxf(v + cv[r] * bv + b2v, 0.f);
            int rl = w * 16 + lk * 4 + r;
            if constexpr (OUT == 0) ((ushort*)LsRaw)[(size_t)rl * KO + col] = f2bf(v);
            else                    ((float*)LsRaw)[(size_t)rl * KO + col] = v;
        }
    }
    __syncthreads();

    if constexpr (OUT == 0) {
        ushort* o = (ushort*)outp;
        constexpr int CH = 64 * KO / 8;
        for (int idx = threadIdx.x; idx < CH; idx += 256) {
            int row = idx / (KO / 8), c8 = idx % (KO / 8);
            if (rowbase + row < N)
                *(bf16x8*)(o + (size_t)(rowbase + row) * ostride + c8 * 8) = ((const bf16x8*)LsRaw)[idx];
        }
    } else {
        float* o = (float*)outp;
        constexpr int CH = 64 * KO / 4;
        for (int idx = threadIdx.x; idx < CH; idx += 256) {
            int row = idx / (KO / 4), c4 = idx % (KO / 4);
            if (rowbase + row < N)
                *(float4*)(o + (size_t)(rowbase + row) * ostride + c4 * 4) = ((const float4*)LsRaw)[idx];
        }
    }
}

// ------------------------------------------------------------------ launch
extern "C" void kernel_launch(void* const* d_in, const int* in_sizes, int n_in,
                              void* d_out, int out_size, void* d_ws, size_t ws_size,
                              hipStream_t stream) {
    const float* x    = (const float*)d_in[0];
    const float* eps  = (const float*)d_in[1];
    const int*   ei   = (const int*)d_in[2];
    const float* w_in  = (const float*)d_in[3];  const float* b_in  = (const float*)d_in[4];
    const float* w_mu0 = (const float*)d_in[5];  const float* b_mu0 = (const float*)d_in[6];
    const float* w_mu  = (const float*)d_in[7];  const float* b_mu  = (const float*)d_in[8];
    const float* w_si0 = (const float*)d_in[9];  const float* b_si0 = (const float*)d_in[10];
    const float* w_si  = (const float*)d_in[11]; const float* b_si  = (const float*)d_in[12];
    const float* w_z   = (const float*)d_in[13]; const float* b_z   = (const float*)d_in[14];
    const float* w_d0  = (const float*)d_in[15]; const float* b_d0  = (const float*)d_in[16];
    const float* w_out = (const float*)d_in[17]; const float* b_out = (const float*)d_in[18];

    const int N = in_sizes[0] / 64;
    const int E = in_sizes[2] / 2;
    const int* srcI = ei;
    const int* dstI = ei + E;

    int shift = 4;
    while (((N >> shift) + 1) > 8192) shift++;
    const int NB = (N >> shift) + 1;

    auto align = [](size_t v) { return (v + 255) & ~(size_t)255; };
    char* wsp = (char*)d_ws;
    size_t off = 0;
    int*    deg       = (int*)(wsp + off);    size_t deg_off = off; off = align(off + (size_t)N * 4);
    int*    bc0       = (int*)(wsp + off);    off = align(off + (size_t)NB * 4);
    int*    bc1       = (int*)(wsp + off);    off = align(off + (size_t)NB * 4);
    size_t  zero_span = off - deg_off;
    float*  cvec      = (float*)(wsp + off);  off = align(off + (size_t)N * 4);
    int*    row_start = (int*)(wsp + off);    off = align(off + (size_t)(N + 1) * 4);
    int*    bin_start = (int*)(wsp + off);    off = align(off + (size_t)(NB + 1) * 4);
    int*    bsum      = (int*)(wsp + off);    off = align(off + 1024 * 4);
    float*  dinv      = (float*)(wsp + off);  off = align(off + (size_t)N * 4);
    float*  bzw       = (float*)(wsp + off);  off = align(off + 128 * 4);
    ushort* P_in      = (ushort*)(wsp + off); off = align(off + 64 * 128 * 2);
    ushort* P_mu0     = (ushort*)(wsp + off); off = align(off + 128 * 128 * 2);
    ushort* P_si0     = (ushort*)(wsp + off); off = align(off + 128 * 128 * 2);
    ushort* P_mu      = (ushort*)(wsp + off); off = align(off + 128 * 64 * 2);
    ushort* P_si      = (ushort*)(wsp + off); off = align(off + 128 * 64 * 2);
    ushort* P_wc      = (ushort*)(wsp + off); off = align(off + 64 * 128 * 2);
    ushort* P_out     = (ushort*)(wsp + off); off = align(off + 128 * 128 * 2);
    uint*   csrp      = (uint*)(wsp + off);   off = align(off + (size_t)(E + 64) * 4);
    int2*   ebuf      = (int2*)(wsp + off);   off = align(off + (size_t)E * 8);  // alias: xb after place2
    ushort* xb        = (ushort*)ebuf;        // [N,64] bf16 x, later ppz
    ushort* B1        = (ushort*)(wsp + off); off = align(off + (size_t)N * 128 * 2);
    ushort* B1lo = B1;                        // [N,64]
    ushort* B1hi = B1 + (size_t)N * 64;       // [N,64]

    float* Cc = (float*)d_out;               // logits f32 [N,128] (final)
    float* M  = Cc + (size_t)N * 128;        // mu f32 (final)
    float* S  = M + (size_t)N * 64;          // si f32 (final)
    ushort* CcLo = (ushort*)Cc;              // bf16 [N,128] scratch: h, later r2
    ushort* CcHi = (ushort*)(Cc + (size_t)N * 64);  // bf16 [N,128] scratch: T (interleaved)
    ushort* Db   = (ushort*)M;               // bf16 [N,128] scratch: ph (dead before smssz writes M)

    const int TB = 256;
    hipMemsetAsync(deg, 0, zero_span, stream);
    counts_kernel<<<256, 1024, 0, stream>>>(dstI, deg, bc0, E, NB, shift);
    dinv_kernel<<<(N + TB - 1) / TB, TB, 0, stream>>>(deg, dinv, N);
    int nbN = (N + 1023) / 1024;
    scan_block_kernel<<<nbN, 1024, 0, stream>>>(deg, row_start, bsum, N);
    scan_partials_kernel<<<1, 1024, 0, stream>>>(bsum, nbN);
    scan_add_kernel<<<nbN, 1024, 0, stream>>>(row_start, bsum, N, E);
    int nbB = (NB + 1023) / 1024;
    scan_block_kernel<<<nbB, 1024, 0, stream>>>(bc0, bin_start, bsum, NB);
    scan_partials_kernel<<<1, 1024, 0, stream>>>(bsum, nbB);
    scan_add_kernel<<<nbB, 1024, 0, stream>>>(bin_start, bsum, NB, E);
    hipMemsetAsync(deg, 0, (size_t)N * 4, stream);   // deg reused as place counter
    scatter_kernel<<<(E + TB - 1) / TB, TB, 0, stream>>>(srcI, dstI, bin_start, bc1, ebuf, E, shift);
    place2_kernel<<<(E + TB - 1) / TB, TB, 0, stream>>>(ebuf, row_start, deg, csrp, dinv, E);
    rowsum_kernel<<<(N + TB - 1) / TB, TB, 0, stream>>>(csrp, row_start, dinv, cvec, N);
    wcpack_kernel<<<(65 * 128 + 255) / 256, 256, 0, stream>>>(w_z, b_z, w_d0, P_wc, bzw);
    megapack_kernel<<<288, 256, 0, stream>>>(w_in, w_mu0, w_si0, w_mu, w_si, w_out,
                                             P_in, P_mu0, P_si0, P_mu, P_si, P_out);
    cvt8_kernel<<<((N * 8) + 255) / 256, 256, 0, stream>>>(x, xb, N * 8);  // ebuf alias dead

    int PG64  = 8 * ((N + 15) / 16);   // sliced 64-wide: 16 nodes/block x 8 slices
    int PG128 = 8 * ((N + 7) / 8);     // sliced 128-wide: 8 nodes/block x 8 slices
    int GB = (N + 63) / 64;

    // 1. px = P(x) -> B1lo [64]
    sprop64_kernel<<<PG64, 256, 0, stream>>>(xb, B1lo, row_start, csrp, dinv, N);
    // 2. h = relu(px@w_in + b) -> CcLo [128]
    mgemm_kernel<64, 128, 2, 0><<<GB, 256, 0, stream>>>(B1lo, (const bf16x8*)P_in, b_in, nullptr, nullptr, CcLo, 128, N);
    // 3. ph = P(h) -> Db [128]
    sprop128_kernel<<<PG128, 256, 0, stream>>>(CcLo, Db, row_start, csrp, dinv, N);
    // 4. fused encoder GEMMs: ph -> T interleaved (CcHi)
    encgemm_kernel<<<GB, 256, 0, stream>>>(Db,
                                           (const bf16x8*)P_mu0, b_mu0, (const bf16x8*)P_mu,
                                           (const bf16x8*)P_si0, b_si0, (const bf16x8*)P_si,
                                           CcHi, N);
    // 5. smssz: sliced prop T -> mu (M f32), si (S f32), z -> B1lo bf16 (ph dead)
    smssz_kernel<<<PG128, 256, 0, stream>>>(CcHi, row_start, csrp, dinv, b_mu, b_si, eps, M, S, B1lo, N);
    // 6. pz = P(z) -> B1hi [64]
    sprop64_kernel<<<PG64, 256, 0, stream>>>(B1lo, B1hi, row_start, csrp, dinv, N);
    // 7. ppz = P(pz) -> xb region (x dead)
    sprop64_kernel<<<PG64, 256, 0, stream>>>(B1hi, xb, row_start, csrp, dinv, N);
    // 8. r2 = relu(ppz@Wc + cvec*bzw + b_d0) -> CcLo [128] (h dead)
    mgemm_kernel<64, 128, 3, 0><<<GB, 256, 0, stream>>>(xb, (const bf16x8*)P_wc, bzw, b_d0, cvec, CcLo, 128, N);
    // 9. pr2 = P(r2) -> B1 [128] (z/pz dead)
    sprop128_kernel<<<PG128, 256, 0, stream>>>(CcLo, B1, row_start, csrp, dinv, N);
    // 10. logits = pr2@w_out + b_out -> Cc f32 (final; reads B1 only)
    mgemm_kernel<128, 128, 1, 1><<<GB, 256, 0, stream>>>(B1, (const bf16x8*)P_out, b_out, nullptr, nullptr, Cc, 128, N);
}

// Round 11
// 642.876 us; speedup vs baseline: 2.4160x; 2.4160x over previous
//
#include <hip/hip_runtime.h>

// VGAE: 8 GCN layers, N=100000, E=1.6M, dims 64/128 — bf16 + MFMA.
// GCN(x,W,b) = P(x)@W + b, P linear. Best-of-measured structure (r8+r9):
// 64-wide props: 2-node software-pipelined waves (pprop). 128-wide: wave-per-node
// DEPTH=2 (bprop). mssz: wave-per-node. Props are at a measured plateau
// (~29G random-row-lines/s); XCD-slicing (r10) regressed 3.5x on FETCH.
// Binned CSR build; encoder 4 GEMMs fused; decoder 1-2 fused via Wc = w_z@w_d0.

typedef short bf16x8 __attribute__((ext_vector_type(8)));
typedef float f32x4 __attribute__((ext_vector_type(4)));

__device__ __forceinline__ ushort f2bf(float f) {           // RNE
    uint x = __float_as_uint(f);
    uint r = x + 0x7FFFu + ((x >> 16) & 1u);
    return (ushort)(r >> 16);
}
__device__ __forceinline__ float bf2f(ushort h) {
    return __uint_as_float(((uint)h) << 16);
}
__device__ __forceinline__ float dot2bf(uint a, uint b, float c) {
    float d;
    asm("v_dot2_f32_bf16 %0, %1, %2, %3" : "=v"(d) : "v"(a), "v"(b), "v"(c));
    return d;
}

// ------------------------------------------------------------------ counts: deg + binned histogram
__global__ __launch_bounds__(1024) void counts_kernel(const int* __restrict__ dst,
        int* __restrict__ deg, int* __restrict__ bc0, int E, int NB, int shift) {
    __shared__ int h[8192];
    for (int j = threadIdx.x; j < NB; j += 1024) h[j] = 0;
    __syncthreads();
    int stride = gridDim.x * 1024;
    for (int i = blockIdx.x * 1024 + threadIdx.x; i < E; i += stride) {
        int d = dst[i];
        atomicAdd(&deg[d], 1);
        atomicAdd(&h[d >> shift], 1);
    }
    __syncthreads();
    for (int j = threadIdx.x; j < NB; j += 1024) {
        int v = h[j];
        if (v) atomicAdd(&bc0[j], v);
    }
}

// ------------------------------------------------------------------ scan (optionally emits dinv from the input values)
__global__ __launch_bounds__(1024) void scan_block_kernel(const int* __restrict__ in,
                                                          int* __restrict__ out,
                                                          int* __restrict__ bsum,
                                                          float* __restrict__ dinv, int n) {
    __shared__ int s[1024];
    int i = blockIdx.x * 1024 + threadIdx.x;
    int v = (i < n) ? in[i] : 0;
    if (dinv && i < n) dinv[i] = rsqrtf((float)(v + 1));
    s[threadIdx.x] = v;
    __syncthreads();
    for (int off = 1; off < 1024; off <<= 1) {
        int t = (threadIdx.x >= off) ? s[threadIdx.x - off] : 0;
        __syncthreads();
        s[threadIdx.x] += t;
        __syncthreads();
    }
    if (i < n) out[i] = s[threadIdx.x] - v;
    if (threadIdx.x == 1023) bsum[blockIdx.x] = s[1023];
}

__global__ __launch_bounds__(1024) void scan_partials_kernel(int* __restrict__ bsum, int nb) {
    __shared__ int s[1024];
    int v = (threadIdx.x < nb) ? bsum[threadIdx.x] : 0;
    s[threadIdx.x] = v;
    __syncthreads();
    for (int off = 1; off < 1024; off <<= 1) {
        int t = (threadIdx.x >= off) ? s[threadIdx.x - off] : 0;
        __syncthreads();
        s[threadIdx.x] += t;
        __syncthreads();
    }
    if (threadIdx.x < nb) bsum[threadIdx.x] = s[threadIdx.x] - v;
}

__global__ __launch_bounds__(1024) void scan_add_kernel(int* __restrict__ arr,
                                                        const int* __restrict__ bsum, int n, int total) {
    int i = blockIdx.x * 1024 + threadIdx.x;
    if (i < n) arr[i] += bsum[blockIdx.x];
    if (i == 0) arr[n] = total;
}

// ------------------------------------------------------------------ bin scatter + place
__global__ void scatter_kernel(const int* __restrict__ src, const int* __restrict__ dst,
                               const int* __restrict__ bin_start, int* __restrict__ bc1,
                               int2* __restrict__ ebuf, int E, int shift) {
    int i = blockIdx.x * blockDim.x + threadIdx.x;
    if (i < E) {
        int d = dst[i];
        int b = d >> shift;
        int pos = bin_start[b] + atomicAdd(&bc1[b], 1);
        ebuf[pos] = make_int2(src[i], d);
    }
}

// csr entry: {src, bf16(weight) in low 16 bits}
__global__ void place2_kernel(const int2* __restrict__ ebuf, const int* __restrict__ row_start,
                              int* __restrict__ cnt, int2* __restrict__ csr,
                              const float* __restrict__ dinv, int E) {
    int i = blockIdx.x * blockDim.x + threadIdx.x;
    if (i < E) {
        int2 e = ebuf[i];
        int pos = row_start[e.y] + atomicAdd(&cnt[e.y], 1);
        csr[pos] = make_int2(e.x, (int)(uint)f2bf(dinv[e.x] * dinv[e.y]));
    }
}

// ------------------------------------------------------------------ cvec[j] = dinv_j^2 + sum_w
__global__ void rowsum_kernel(const int2* __restrict__ csr, const int* __restrict__ row_start,
                              const float* __restrict__ dinv, float* __restrict__ cvec, int N) {
    int j = blockIdx.x * blockDim.x + threadIdx.x;
    if (j >= N) return;
    float s = dinv[j] * dinv[j];
    int b = row_start[j], e = row_start[j + 1];
    for (int k = b; k < e; ++k) s += bf2f((ushort)((uint)csr[k].y & 0xFFFFu));
    cvec[j] = s;
}

// ------------------------------------------------------------------ Wc = w_z@w_d0 packed bf16, bzw = b_z@w_d0
__global__ void wcpack_kernel(const float* __restrict__ w_z, const float* __restrict__ b_z,
                              const float* __restrict__ w_d0,
                              ushort* __restrict__ P_wc, float* __restrict__ bzw) {
    int o = blockIdx.x * 256 + threadIdx.x;
    if (o >= 65 * 128) return;
    int i = o >> 7, j = o & 127;
    float s = 0.f;
    for (int k = 0; k < 128; ++k) {
        float a = (i < 64) ? w_z[i * 128 + k] : b_z[k];
        s = fmaf(a, w_d0[k * 128 + j], s);
    }
    if (i < 64) {
        int c = j >> 4, kb = i >> 5, l = ((i >> 3) & 3) * 16 + (j & 15), e = i & 7;
        P_wc[(size_t)((c * 2 + kb) * 64 + l) * 8 + e] = f2bf(s);
    } else bzw[j] = s;
}

// ------------------------------------------------------------------ weight packs (6 weights, 1 launch)
__device__ __forceinline__ void pack_one(const float* __restrict__ W, ushort* __restrict__ P,
                                         int KI, int KO, int idx) {
    if (idx >= KI * KO) return;
    int e = idx & 7, l = (idx >> 3) & 63, t = idx >> 9;
    int KB = KI / 32;
    int c = t / KB, kb = t % KB;
    int k = kb * 32 + ((l >> 4) << 3) + e, col = c * 16 + (l & 15);
    P[idx] = f2bf(W[(size_t)k * KO + col]);
}

__global__ void megapack_kernel(const float* w_in, const float* w_mu0, const float* w_si0,
                                const float* w_mu, const float* w_si, const float* w_out,
                                ushort* P_in, ushort* P_mu0, ushort* P_si0,
                                ushort* P_mu, ushort* P_si, ushort* P_out) {
    int b = blockIdx.x, tid = threadIdx.x;
    if (b < 32)       pack_one(w_in,  P_in,  64, 128,  (b - 0)   * 256 + tid);
    else if (b < 96)  pack_one(w_mu0, P_mu0, 128, 128, (b - 32)  * 256 + tid);
    else if (b < 160) pack_one(w_si0, P_si0, 128, 128, (b - 96)  * 256 + tid);
    else if (b < 192) pack_one(w_mu,  P_mu,  128, 64,  (b - 160) * 256 + tid);
    else if (b < 224) pack_one(w_si,  P_si,  128, 64,  (b - 192) * 256 + tid);
    else              pack_one(w_out, P_out, 128, 128, (b - 224) * 256 + tid);
}

// ------------------------------------------------------------------ f32 -> bf16
__global__ void cvt8_kernel(const float* __restrict__ in, ushort* __restrict__ out, int n8) {
    int i = blockIdx.x * 256 + threadIdx.x;
    if (i >= n8) return;
    float4 a = ((const float4*)in)[i * 2];
    float4 b = ((const float4*)in)[i * 2 + 1];
    bf16x8 o;
    o[0] = (short)f2bf(a.x); o[1] = (short)f2bf(a.y);
    o[2] = (short)f2bf(a.z); o[3] = (short)f2bf(a.w);
    o[4] = (short)f2bf(b.x); o[5] = (short)f2bf(b.y);
    o[6] = (short)f2bf(b.z); o[7] = (short)f2bf(b.w);
    ((bf16x8*)out)[i] = o;
}

// ================================================================== gather helpers
// (A) gather_pairs: DEPTH edge-pair batches, wave-per-node (used by 128-wide props).
template <int W, int DEPTH>
__device__ __forceinline__ void gather_pairs(float* acc, const ushort* __restrict__ xb,
        const int2* __restrict__ csr, int node, int beg, int end, int sub, int f8) {
    constexpr int SLOTS = 64 / (W / 8);
    for (int base = beg; base < end; base += 2 * SLOTS * DEPTH) {
        int sidx[DEPTH][2];
        uint wv[DEPTH][2];
        #pragma unroll
        for (int d = 0; d < DEPTH; ++d) {
            int e0 = base + 2 * (sub + SLOTS * d), e1 = e0 + 1;
            int2 p0 = csr[e0 < end ? e0 : beg];
            int2 p1 = csr[e1 < end ? e1 : beg];
            sidx[d][0] = (e0 < end) ? p0.x : node;
            sidx[d][1] = (e1 < end) ? p1.x : node;
            wv[d][0] = (e0 < end) ? (uint)p0.y : 0u;
            wv[d][1] = (e1 < end) ? (uint)p1.y : 0u;
        }
        uint4 rv[DEPTH][2];
        #pragma unroll
        for (int d = 0; d < DEPTH; ++d) {
            rv[d][0] = *(const uint4*)(xb + (size_t)sidx[d][0] * W + f8 * 8);
            rv[d][1] = *(const uint4*)(xb + (size_t)sidx[d][1] * W + f8 * 8);
        }
        #pragma unroll
        for (int d = 0; d < DEPTH; ++d) {
            uint wpk = __builtin_amdgcn_perm(wv[d][1], wv[d][0], 0x05040100u);
            uint4 v0 = rv[d][0], v1 = rv[d][1];
            uint t;
            t = __builtin_amdgcn_perm(v1.x, v0.x, 0x05040100u); acc[0] = dot2bf(t, wpk, acc[0]);
            t = __builtin_amdgcn_perm(v1.x, v0.x, 0x07060302u); acc[1] = dot2bf(t, wpk, acc[1]);
            t = __builtin_amdgcn_perm(v1.y, v0.y, 0x05040100u); acc[2] = dot2bf(t, wpk, acc[2]);
            t = __builtin_amdgcn_perm(v1.y, v0.y, 0x07060302u); acc[3] = dot2bf(t, wpk, acc[3]);
            t = __builtin_amdgcn_perm(v1.z, v0.z, 0x05040100u); acc[4] = dot2bf(t, wpk, acc[4]);
            t = __builtin_amdgcn_perm(v1.z, v0.z, 0x07060302u); acc[5] = dot2bf(t, wpk, acc[5]);
            t = __builtin_amdgcn_perm(v1.w, v0.w, 0x05040100u); acc[6] = dot2bf(t, wpk, acc[6]);
            t = __builtin_amdgcn_perm(v1.w, v0.w, 0x07060302u); acc[7] = dot2bf(t, wpk, acc[7]);
        }
    }
}

// (B) GS state machine: 2-node pipelined wave (used by 64-wide props).
template <int W>
struct GS {
    static constexpr int L = W / 8;
    static constexpr int SLOTS = 64 / L;
    static constexpr int PP = 16 / (2 * SLOTS);
    int2 c[2 * PP];
    uint4 r[2 * PP];
};

template <int W>
__device__ __forceinline__ void g_csr(GS<W>& st, const int2* __restrict__ csr,
                                      int base, int beg, int end, int sub) {
    int safe = (end > beg) ? beg : 0;
    #pragma unroll
    for (int p = 0; p < GS<W>::PP; ++p) {
        int e0 = base + 2 * (sub + GS<W>::SLOTS * p);
        st.c[2 * p]     = csr[e0 < end ? e0 : safe];
        st.c[2 * p + 1] = csr[e0 + 1 < end ? e0 + 1 : safe];
    }
}

template <int W>
__device__ __forceinline__ void g_rows(GS<W>& st, const ushort* __restrict__ xb, int f8) {
    #pragma unroll
    for (int i = 0; i < 2 * GS<W>::PP; ++i)
        st.r[i] = *(const uint4*)(xb + (size_t)st.c[i].x * W + f8 * 8);
}

template <int W>
__device__ __forceinline__ void g_consume(GS<W>& st, float* acc, int base, int end, int sub) {
    #pragma unroll
    for (int p = 0; p < GS<W>::PP; ++p) {
        int e0 = base + 2 * (sub + GS<W>::SLOTS * p);
        uint w0 = (e0 < end) ? (uint)st.c[2 * p].y : 0u;
        uint w1 = (e0 + 1 < end) ? (uint)st.c[2 * p + 1].y : 0u;
        uint wpk = __builtin_amdgcn_perm(w1, w0, 0x05040100u);
        uint4 v0 = st.r[2 * p], v1 = st.r[2 * p + 1];
        uint t;
        t = __builtin_amdgcn_perm(v1.x, v0.x, 0x05040100u); acc[0] = dot2bf(t, wpk, acc[0]);
        t = __builtin_amdgcn_perm(v1.x, v0.x, 0x07060302u); acc[1] = dot2bf(t, wpk, acc[1]);
        t = __builtin_amdgcn_perm(v1.y, v0.y, 0x05040100u); acc[2] = dot2bf(t, wpk, acc[2]);
        t = __builtin_amdgcn_perm(v1.y, v0.y, 0x07060302u); acc[3] = dot2bf(t, wpk, acc[3]);
        t = __builtin_amdgcn_perm(v1.z, v0.z, 0x05040100u); acc[4] = dot2bf(t, wpk, acc[4]);
        t = __builtin_amdgcn_perm(v1.z, v0.z, 0x07060302u); acc[5] = dot2bf(t, wpk, acc[5]);
        t = __builtin_amdgcn_perm(v1.w, v0.w, 0x05040100u); acc[6] = dot2bf(t, wpk, acc[6]);
        t = __builtin_amdgcn_perm(v1.w, v0.w, 0x07060302u); acc[7] = dot2bf(t, wpk, acc[7]);
    }
}

// ------------------------------------------------------------------ pprop: 2 nodes/wave pipelined (64-wide)
template <int W>
__global__ __launch_bounds__(256) void pprop_kernel(const ushort* __restrict__ xb,
        ushort* __restrict__ out, const int* __restrict__ row_start,
        const int2* __restrict__ csr, const float* __restrict__ dinv, int N) {
    constexpr int L = W / 8;
    int wave = threadIdx.x >> 6, lane = threadIdx.x & 63;
    int nb = (blockIdx.x * 4 + wave) * 2;
    if (nb >= N) return;
    int sub = lane / L, f8 = lane % L;
    bool v1 = (nb + 1) < N;
    int n0 = nb, n1 = v1 ? nb + 1 : nb;

    int2 rs01 = *(const int2*)&row_start[nb];
    int rs2 = row_start[v1 ? nb + 2 : nb + 1];
    int beg0 = rs01.x, end0 = rs01.y;
    int beg1 = rs01.y, end1 = v1 ? rs2 : rs01.y;

    float d20 = dinv[n0], d21 = dinv[n1];
    bf16x8 sv0 = *(const bf16x8*)(xb + (size_t)n0 * W + f8 * 8);
    bf16x8 sv1 = *(const bf16x8*)(xb + (size_t)n1 * W + f8 * 8);

    GS<W> sA, sB, sA2, sB2;
    g_csr(sA, csr, beg0, beg0, end0, sub);
    g_csr(sB, csr, beg1, beg1, end1, sub);
    g_csr(sA2, csr, beg0 + 16, beg0, end0, sub);
    g_csr(sB2, csr, beg1 + 16, beg1, end1, sub);
    g_rows(sA, xb, f8);
    g_rows(sB, xb, f8);

    float a0[8] = {}, a1[8] = {};
    bool m0 = (beg0 + 16) < end0, m1 = (beg1 + 16) < end1;
    g_consume(sA, a0, beg0, end0, sub);
    if (m0) g_rows(sA2, xb, f8);
    g_consume(sB, a1, beg1, end1, sub);
    if (m1) g_rows(sB2, xb, f8);
    if (m0) {
        g_consume(sA2, a0, beg0 + 16, end0, sub);
        for (int base = beg0 + 32; base < end0; base += 16) {
            GS<W> t;
            g_csr(t, csr, base, beg0, end0, sub);
            g_rows(t, xb, f8);
            g_consume(t, a0, base, end0, sub);
        }
    }
    if (m1) {
        g_consume(sB2, a1, beg1 + 16, end1, sub);
        for (int base = beg1 + 32; base < end1; base += 16) {
            GS<W> t;
            g_csr(t, csr, base, beg1, end1, sub);
            g_rows(t, xb, f8);
            g_consume(t, a1, base, end1, sub);
        }
    }

    #pragma unroll
    for (int m = L; m < 64; m <<= 1) {
        #pragma unroll
        for (int q = 0; q < 8; ++q) {
            a0[q] += __shfl_xor(a0[q], m);
            a1[q] += __shfl_xor(a1[q], m);
        }
    }
    if (sub == 0) {
        float d2 = d20 * d20;
        bf16x8 o0;
        #pragma unroll
        for (int q = 0; q < 8; ++q) o0[q] = (short)f2bf(fmaf(d2, bf2f((ushort)sv0[q]), a0[q]));
        *(bf16x8*)(out + (size_t)n0 * W + f8 * 8) = o0;
        if (v1) {
            float e2 = d21 * d21;
            bf16x8 o1;
            #pragma unroll
            for (int q = 0; q < 8; ++q) o1[q] = (short)f2bf(fmaf(e2, bf2f((ushort)sv1[q]), a1[q]));
            *(bf16x8*)(out + (size_t)n1 * W + f8 * 8) = o1;
        }
    }
}

// ------------------------------------------------------------------ bprop: wave-per-node DEPTH=2 (128-wide)
template <int W, int DEPTH>
__global__ __launch_bounds__(256) void bprop_kernel(const ushort* __restrict__ xb,
        ushort* __restrict__ out, const int* __restrict__ row_start,
        const int2* __restrict__ csr, const float* __restrict__ dinv, int N) {
    constexpr int L = W / 8;
    int wave = threadIdx.x >> 6, lane = threadIdx.x & 63;
    int node = blockIdx.x * 4 + wave;
    if (node >= N) return;
    int sub = lane / L, f8 = lane % L;
    int beg = row_start[node], end = row_start[node + 1];
    float d2 = dinv[node]; d2 *= d2;
    float acc[8] = {};
    gather_pairs<W, DEPTH>(acc, xb, csr, node, beg, end, sub, f8);
    #pragma unroll
    for (int m = L; m < 64; m <<= 1) {
        #pragma unroll
        for (int q = 0; q < 8; ++q) acc[q] += __shfl_xor(acc[q], m);
    }
    if (sub != 0) return;
    bf16x8 sv = *(const bf16x8*)(xb + (size_t)node * W + f8 * 8);
    bf16x8 oz;
    #pragma unroll
    for (int q = 0; q < 8; ++q) oz[q] = (short)f2bf(fmaf(d2, bf2f((ushort)sv[q]), acc[q]));
    *(bf16x8*)(out + (size_t)node * W + f8 * 8) = oz;
}

// ------------------------------------------------------------------ mssz: 128-prop of T=[tmu|tsi] -> mu, si, z
__global__ __launch_bounds__(256) void mssz_kernel(const ushort* __restrict__ T,
        const int* __restrict__ row_start, const int2* __restrict__ csr,
        const float* __restrict__ dinv, const float* __restrict__ b_mu,
        const float* __restrict__ b_si, const float* __restrict__ eps,
        float* __restrict__ M, float* __restrict__ S, ushort* __restrict__ zb, int N) {
    constexpr int L = 16;
    int wave = threadIdx.x >> 6, lane = threadIdx.x & 63;
    int node = blockIdx.x * 4 + wave;
    if (node >= N) return;
    int sub = lane / L, f8 = lane % L;
    int beg = row_start[node], end = row_start[node + 1];
    float d2 = dinv[node]; d2 *= d2;
    float acc[8] = {};
    gather_pairs<128, 2>(acc, T, csr, node, beg, end, sub, f8);
    #pragma unroll
    for (int m = 16; m < 64; m <<= 1) {
        #pragma unroll
        for (int q = 0; q < 8; ++q) acc[q] += __shfl_xor(acc[q], m);
    }
    if (sub != 0) return;
    bf16x8 sv = *(const bf16x8*)(T + (size_t)node * 128 + f8 * 8);
    #pragma unroll
    for (int q = 0; q < 8; ++q) acc[q] = fmaf(d2, bf2f((ushort)sv[q]), acc[q]);

    bool is_mu = (f8 < 8);
    const float* bp = is_mu ? b_mu : b_si;
    int o = (f8 & 7) * 8;
    float val[8];
    #pragma unroll
    for (int q = 0; q < 8; ++q) {
        float t = acc[q] + bp[o + q];
        val[q] = is_mu ? fmaxf(t, 0.f) : 1.f / (1.f + __expf(-t));
    }
    if (is_mu) {
        *(float4*)&M[(size_t)node * 64 + o]     = make_float4(val[0], val[1], val[2], val[3]);
        *(float4*)&M[(size_t)node * 64 + o + 4] = make_float4(val[4], val[5], val[6], val[7]);
    } else {
        *(float4*)&S[(size_t)node * 64 + o]     = make_float4(val[0], val[1], val[2], val[3]);
        *(float4*)&S[(size_t)node * 64 + o + 4] = make_float4(val[4], val[5], val[6], val[7]);
    }
    float oth[8];
    #pragma unroll
    for (int q = 0; q < 8; ++q) oth[q] = __shfl_xor(val[q], 8);
    if (is_mu) {   // lane holds mu (val) + si (oth): z = mu + si*eps
        float4 e0v = *(const float4*)&eps[(size_t)node * 64 + o];
        float4 e1v = *(const float4*)&eps[(size_t)node * 64 + o + 4];
        float ev[8] = {e0v.x, e0v.y, e0v.z, e0v.w, e1v.x, e1v.y, e1v.z, e1v.w};
        bf16x8 z;
        #pragma unroll
        for (int q = 0; q < 8; ++q) z[q] = (short)f2bf(fmaf(oth[q], ev[q], val[q]));
        *(bf16x8*)(zb + (size_t)node * 64 + o) = z;
    }
}

// ------------------------------------------------------------------ fused encoder GEMM chain
__global__ __launch_bounds__(256) void encgemm_kernel(const ushort* __restrict__ PH,
        const bf16x8* __restrict__ Pmu0, const float* __restrict__ b_mu0,
        const bf16x8* __restrict__ Pmu,
        const bf16x8* __restrict__ Psi0, const float* __restrict__ b_si0,
        const bf16x8* __restrict__ Psi,
        ushort* __restrict__ T, int N) {
    constexpr int STR = 136;
    __shared__ __align__(16) ushort Ls[64 * STR];
    int w = threadIdx.x >> 6, l = threadIdx.x & 63;
    int lr = l & 15, lk = l >> 4;
    int rowbase = blockIdx.x * 64;
    int arow = rowbase + w * 16 + lr; if (arow > N - 1) arow = N - 1;

    bf16x8 aph[4];
    const ushort* pp = PH + (size_t)arow * 128 + lk * 8;
    #pragma unroll
    for (int kb = 0; kb < 4; ++kb) aph[kb] = *(const bf16x8*)(pp + kb * 32);

    int crow0 = w * 16 + lk * 4;
    int afrow = w * 16 + lr;

    #pragma unroll
    for (int c = 0; c < 8; ++c) {
        f32x4 acc = {0.f, 0.f, 0.f, 0.f};
        #pragma unroll
        for (int kb = 0; kb < 4; ++kb)
            acc = __builtin_amdgcn_mfma_f32_16x16x32_bf16(aph[kb], Pmu0[((size_t)c * 4 + kb) * 64 + l], acc, 0, 0, 0);
        float bv = b_mu0[c * 16 + lr];
        #pragma unroll
        for (int r = 0; r < 4; ++r)
            Ls[(crow0 + r) * STR + c * 16 + lr] = f2bf(fmaxf(acc[r] + bv, 0.f));
    }
    __syncthreads();
    bf16x8 am[4];
    #pragma unroll
    for (int kb = 0; kb < 4; ++kb) am[kb] = *(const bf16x8*)&Ls[afrow * STR + kb * 32 + lk * 8];
    f32x4 tmu[4];
    #pragma unroll
    for (int c = 0; c < 4; ++c) {
        f32x4 acc = {0.f, 0.f, 0.f, 0.f};
        #pragma unroll
        for (int kb = 0; kb < 4; ++kb)
            acc = __builtin_amdgcn_mfma_f32_16x16x32_bf16(am[kb], Pmu[((size_t)c * 4 + kb) * 64 + l], acc, 0, 0, 0);
        tmu[c] = acc;
    }
    __syncthreads();
    #pragma unroll
    for (int c = 0; c < 8; ++c) {
        f32x4 acc = {0.f, 0.f, 0.f, 0.f};
        #pragma unroll
        for (int kb = 0; kb < 4; ++kb)
            acc = __builtin_amdgcn_mfma_f32_16x16x32_bf16(aph[kb], Psi0[((size_t)c * 4 + kb) * 64 + l], acc, 0, 0, 0);
        float bv = b_si0[c * 16 + lr];
        #pragma unroll
        for (int r = 0; r < 4; ++r)
            Ls[(crow0 + r) * STR + c * 16 + lr] = f2bf(fmaxf(acc[r] + bv, 0.f));
    }
    __syncthreads();
    #pragma unroll
    for (int kb = 0; kb < 4; ++kb) am[kb] = *(const bf16x8*)&Ls[afrow * STR + kb * 32 + lk * 8];
    f32x4 tsi[4];
    #pragma unroll
    for (int c = 0; c < 4; ++c) {
        f32x4 acc = {0.f, 0.f, 0.f, 0.f};
        #pragma unroll
        for (int kb = 0; kb < 4; ++kb)
            acc = __builtin_amdgcn_mfma_f32_16x16x32_bf16(am[kb], Psi[((size_t)c * 4 + kb) * 64 + l], acc, 0, 0, 0);
        tsi[c] = acc;
    }
    __syncthreads();
    #pragma unroll
    for (int c = 0; c < 4; ++c) {
        #pragma unroll
        for (int r = 0; r < 4; ++r) {
            Ls[(crow0 + r) * STR + c * 16 + lr]      = f2bf(tmu[c][r]);
            Ls[(crow0 + r) * STR + 64 + c * 16 + lr] = f2bf(tsi[c][r]);
        }
    }
    __syncthreads();
    for (int idx = threadIdx.x; idx < 64 * 16; idx += 256) {
        int row = idx >> 4, c8 = idx & 15;
        if (rowbase + row < N) {
            bf16x8 vv = *(const bf16x8*)&Ls[row * STR + c8 * 8];
            *(bf16x8*)(T + (size_t)(rowbase + row) * 128 + c8 * 8) = vv;
        }
    }
}

// ------------------------------------------------------------------ MFMA GEMM
template <int KI, int KO, int EPI, int OUT>
__global__ __launch_bounds__(256) void mgemm_kernel(const ushort* __restrict__ Xb,
                                                    const bf16x8* __restrict__ Wp,
                                                    const float* __restrict__ bias,
                                                    const float* __restrict__ bias2,
                                                    const float* __restrict__ cvec,
                                                    void* __restrict__ outp, int ostride, int N) {
    constexpr int KB = KI / 32;
    constexpr int CT = KO / 16;
    constexpr size_t LSB = (OUT == 1) ? (size_t)64 * KO * 4 : (size_t)64 * KO * 2;
    __shared__ __align__(16) char LsRaw[LSB];

    int w = threadIdx.x >> 6, l = threadIdx.x & 63;
    int lr = l & 15, lk = l >> 4;
    int rowbase = blockIdx.x * 64;
    int r0 = rowbase + w * 16;

    int arow = r0 + lr; if (arow > N - 1) arow = N - 1;
    bf16x8 a[KB];
    const ushort* xp = Xb + (size_t)arow * KI + lk * 8;
    #pragma unroll
    for (int kb = 0; kb < KB; ++kb) a[kb] = *(const bf16x8*)(xp + kb * 32);

    float cv[4];
    if constexpr (EPI == 3) {
        #pragma unroll
        for (int r = 0; r < 4; ++r) {
            int rr = r0 + lk * 4 + r;
            cv[r] = cvec[rr < N ? rr : 0];
        }
    }

    #pragma unroll
    for (int c = 0; c < CT; ++c) {
        f32x4 acc = {0.f, 0.f, 0.f, 0.f};
        #pragma unroll
        for (int kb = 0; kb < KB; ++kb)
            acc = __builtin_amdgcn_mfma_f32_16x16x32_bf16(a[kb], Wp[((size_t)c * KB + kb) * 64 + l], acc, 0, 0, 0);
        int col = c * 16 + lr;
        float bv = 0.f, b2v = 0.f;
        if constexpr (EPI >= 1) bv = bias[col];
        if constexpr (EPI == 3) b2v = bias2[col];
        #pragma unroll
        for (int r = 0; r < 4; ++r) {
            float v = acc[r];
            if constexpr (EPI == 1) v += bv;
            if constexpr (EPI == 2) v = fmaxf(v + bv, 0.f);
            if constexpr (EPI == 3) v = fmaxf(v + cv[r] * bv + b2v, 0.f);
            int rl = w * 16 + lk * 4 + r;
            if constexpr (OUT == 0) ((ushort*)LsRaw)[(size_t)rl * KO + col] = f2bf(v);
            else                    ((float*)LsRaw)[(size_t)rl * KO + col] = v;
        }
    }
    __syncthreads();

    if constexpr (OUT == 0) {
        ushort* o = (ushort*)outp;
        constexpr int CH = 64 * KO / 8;
        for (int idx = threadIdx.x; idx < CH; idx += 256) {
            int row = idx / (KO / 8), c8 = idx % (KO / 8);
            if (rowbase + row < N)
                *(bf16x8*)(o + (size_t)(rowbase + row) * ostride + c8 * 8) = ((const bf16x8*)LsRaw)[idx];
        }
    } else {
        float* o = (float*)outp;
        constexpr int CH = 64 * KO / 4;
        for (int idx = threadIdx.x; idx < CH; idx += 256) {
            int row = idx / (KO / 4), c4 = idx % (KO / 4);
            if (rowbase + row < N)
                *(float4*)(o + (size_t)(rowbase + row) * ostride + c4 * 4) = ((const float4*)LsRaw)[idx];
        }
    }
}

// ------------------------------------------------------------------ launch
extern "C" void kernel_launch(void* const* d_in, const int* in_sizes, int n_in,
                              void* d_out, int out_size, void* d_ws, size_t ws_size,
                              hipStream_t stream) {
    const float* x    = (const float*)d_in[0];
    const float* eps  = (const float*)d_in[1];
    const int*   ei   = (const int*)d_in[2];
    const float* w_in  = (const float*)d_in[3];  const float* b_in  = (const float*)d_in[4];
    const float* w_mu0 = (const float*)d_in[5];  const float* b_mu0 = (const float*)d_in[6];
    const float* w_mu  = (const float*)d_in[7];  const float* b_mu  = (const float*)d_in[8];
    const float* w_si0 = (const float*)d_in[9];  const float* b_si0 = (const float*)d_in[10];
    const float* w_si  = (const float*)d_in[11]; const float* b_si  = (const float*)d_in[12];
    const float* w_z   = (const float*)d_in[13]; const float* b_z   = (const float*)d_in[14];
    const float* w_d0  = (const float*)d_in[15]; const float* b_d0  = (const float*)d_in[16];
    const float* w_out = (const float*)d_in[17]; const float* b_out = (const float*)d_in[18];

    const int N = in_sizes[0] / 64;
    const int E = in_sizes[2] / 2;
    const int* srcI = ei;
    const int* dstI = ei + E;

    int shift = 4;
    while (((N >> shift) + 1) > 8192) shift++;
    const int NB = (N >> shift) + 1;

    auto align = [](size_t v) { return (v + 255) & ~(size_t)255; };
    char* wsp = (char*)d_ws;
    size_t off = 0;
    int*    deg       = (int*)(wsp + off);    size_t deg_off = off; off = align(off + (size_t)N * 4);
    int*    bc0       = (int*)(wsp + off);    off = align(off + (size_t)NB * 4);
    int*    bc1       = (int*)(wsp + off);    off = align(off + (size_t)NB * 4);
    size_t  zero_span = off - deg_off;
    float*  cvec      = (float*)(wsp + off);  off = align(off + (size_t)N * 4);
    int*    row_start = (int*)(wsp + off);    off = align(off + (size_t)(N + 1) * 4);
    int*    bin_start = (int*)(wsp + off);    off = align(off + (size_t)(NB + 1) * 4);
    int*    bsum      = (int*)(wsp + off);    off = align(off + 1024 * 4);
    float*  dinv      = (float*)(wsp + off);  off = align(off + (size_t)N * 4);
    float*  bzw       = (float*)(wsp + off);  off = align(off + 128 * 4);
    ushort* P_in      = (ushort*)(wsp + off); off = align(off + 64 * 128 * 2);
    ushort* P_mu0     = (ushort*)(wsp + off); off = align(off + 128 * 128 * 2);
    ushort* P_si0     = (ushort*)(wsp + off); off = align(off + 128 * 128 * 2);
    ushort* P_mu      = (ushort*)(wsp + off); off = align(off + 128 * 64 * 2);
    ushort* P_si      = (ushort*)(wsp + off); off = align(off + 128 * 64 * 2);
    ushort* P_wc      = (ushort*)(wsp + off); off = align(off + 64 * 128 * 2);
    ushort* P_out     = (ushort*)(wsp + off); off = align(off + 128 * 128 * 2);
    int2*   csr       = (int2*)(wsp + off);   off = align(off + (size_t)E * 8);
    int2*   ebuf      = (int2*)(wsp + off);   off = align(off + (size_t)E * 8);  // alias: xb after place2
    ushort* xb        = (ushort*)ebuf;        // [N,64] bf16 x, later ppz
    ushort* B1        = (ushort*)(wsp + off); off = align(off + (size_t)N * 128 * 2);
    ushort* B1lo = B1;                        // [N,64]
    ushort* B1hi = B1 + (size_t)N * 64;       // [N,64]

    float* Cc = (float*)d_out;               // logits f32 [N,128] (final)
    float* M  = Cc + (size_t)N * 128;        // mu f32 (final)
    float* S  = M + (size_t)N * 64;          // si f32 (final)
    ushort* CcLo = (ushort*)Cc;              // bf16 [N,128] scratch: h, later r2
    ushort* CcHi = (ushort*)(Cc + (size_t)N * 64);  // bf16 [N,128] scratch: T=[tmu|tsi]
    ushort* Db   = (ushort*)M;               // bf16 [N,128] scratch: ph (dead before mssz writes M)

    const int TB = 256;
    hipMemsetAsync(deg, 0, zero_span, stream);
    counts_kernel<<<256, 1024, 0, stream>>>(dstI, deg, bc0, E, NB, shift);
    int nbN = (N + 1023) / 1024;
    scan_block_kernel<<<nbN, 1024, 0, stream>>>(deg, row_start, bsum, dinv, N);  // also emits dinv
    scan_partials_kernel<<<1, 1024, 0, stream>>>(bsum, nbN);
    scan_add_kernel<<<nbN, 1024, 0, stream>>>(row_start, bsum, N, E);
    int nbB = (NB + 1023) / 1024;
    scan_block_kernel<<<nbB, 1024, 0, stream>>>(bc0, bin_start, bsum, nullptr, NB);
    scan_partials_kernel<<<1, 1024, 0, stream>>>(bsum, nbB);
    scan_add_kernel<<<nbB, 1024, 0, stream>>>(bin_start, bsum, NB, E);
    hipMemsetAsync(deg, 0, (size_t)N * 4, stream);   // deg reused as place counter
    scatter_kernel<<<(E + TB - 1) / TB, TB, 0, stream>>>(srcI, dstI, bin_start, bc1, ebuf, E, shift);
    place2_kernel<<<(E + TB - 1) / TB, TB, 0, stream>>>(ebuf, row_start, deg, csr, dinv, E);
    rowsum_kernel<<<(N + TB - 1) / TB, TB, 0, stream>>>(csr, row_start, dinv, cvec, N);
    wcpack_kernel<<<(65 * 128 + 255) / 256, 256, 0, stream>>>(w_z, b_z, w_d0, P_wc, bzw);
    megapack_kernel<<<288, 256, 0, stream>>>(w_in, w_mu0, w_si0, w_mu, w_si, w_out,
                                             P_in, P_mu0, P_si0, P_mu, P_si, P_out);
    cvt8_kernel<<<((N * 8) + 255) / 256, 256, 0, stream>>>(x, xb, N * 8);  // ebuf alias dead

    int PGP = (N + 7) / 8;       // pprop: 4 waves x 2 nodes
    int PGB = (N + 3) / 4;       // bprop/mssz: 4 waves x 1 node
    int GB  = (N + 63) / 64;

    // 1. px = P(x) -> B1lo [64]
    pprop_kernel<64><<<PGP, 256, 0, stream>>>(xb, B1lo, row_start, csr, dinv, N);
    // 2. h = relu(px@w_in + b) -> CcLo [128]
    mgemm_kernel<64, 128, 2, 0><<<GB, 256, 0, stream>>>(B1lo, (const bf16x8*)P_in, b_in, nullptr, nullptr, CcLo, 128, N);
    // 3. ph = P(h) -> Db [128]
    bprop_kernel<128, 2><<<PGB, 256, 0, stream>>>(CcLo, Db, row_start, csr, dinv, N);
    // 4. fused encoder GEMMs: ph -> T=[tmu|tsi] (CcHi)
    encgemm_kernel<<<GB, 256, 0, stream>>>(Db,
                                           (const bf16x8*)P_mu0, b_mu0, (const bf16x8*)P_mu,
                                           (const bf16x8*)P_si0, b_si0, (const bf16x8*)P_si,
                                           CcHi, N);
    // 5. mssz: prop T -> mu (M f32), si (S f32), z -> B1lo bf16 (ph dead)
    mssz_kernel<<<PGB, 256, 0, stream>>>(CcHi, row_start, csr, dinv, b_mu, b_si, eps, M, S, B1lo, N);
    // 6. pz = P(z) -> B1hi [64]
    pprop_kernel<64><<<PGP, 256, 0, stream>>>(B1lo, B1hi, row_start, csr, dinv, N);
    // 7. ppz = P(pz) -> xb region (x dead)
    pprop_kernel<64><<<PGP, 256, 0, stream>>>(B1hi, xb, row_start, csr, dinv, N);
    // 8. r2 = relu(ppz@Wc + cvec*bzw + b_d0) -> CcLo [128] (h dead)
    mgemm_kernel<64, 128, 3, 0><<<GB, 256, 0, stream>>>(xb, (const bf16x8*)P_wc, bzw, b_d0, cvec, CcLo, 128, N);
    // 9. pr2 = P(r2) -> B1 [128] (z/pz dead)
    bprop_kernel<128, 2><<<PGB, 256, 0, stream>>>(CcLo, B1, row_start, csr, dinv, N);
    // 10. logits = pr2@w_out + b_out -> Cc f32 (final; reads B1 only)
    mgemm_kernel<128, 128, 1, 1><<<GB, 256, 0, stream>>>(B1, (const bf16x8*)P_out, b_out, nullptr, nullptr, Cc, 128, N);
}